// Round 2
// baseline (380.277 us; speedup 1.0000x reference)
//
#include <hip/hip_runtime.h>

#define SEQ_N 1024   // sequence length (n == m == 1024)
#define BATCH 64     // batch size

// One block per batch element. Thread t owns DP row i = t for the whole
// sweep. Anti-diagonal wavefront: at step k, thread t computes cell
// (i=t, j=k-t) when 0 <= k-t < SEQ_N.
//
//   left = D[t, j-1]   -> own `cur` register from previous step
//   up   = D[t-1, j]   -> neighbor's value from previous diagonal (LDS)
//   diag = D[t-1, j-1] -> neighbor's value from 2 diagonals ago
//                         (= previous step's `up`, kept in a register)
//
// Double-buffered LDS diagonal exchange; single __syncthreads at loop top
// orders write(iter k) -> read(iter k+1) AND read(iter k) -> write(iter k+1).
__global__ __launch_bounds__(SEQ_N) void dtw_kernel(const float* __restrict__ x,
                                                    const float* __restrict__ y,
                                                    float* __restrict__ dists) {
    __shared__ float sy[SEQ_N];
    __shared__ float dbuf[2][SEQ_N];

    const int b = blockIdx.x;
    const int t = threadIdx.x;

    sy[t] = y[b * SEQ_N + t];
    const float xt = x[b * SEQ_N + t];

    float cur = 0.0f;      // D[t, j] most recently computed by this thread
    float up_prev = 0.0f;  // neighbor's value from 2 diagonals ago

    for (int k = 0; k < 2 * SEQ_N - 1; ++k) {
        __syncthreads();
        const int j = k - t;
        const bool active = (j >= 0) && (j < SEQ_N);

        if (active) {
            float up = 0.0f;
            if (t > 0) up = dbuf[(k & 1) ^ 1][t - 1];  // written at iter k-1

            const float d = fabsf(xt - sy[j]);
            float val;
            if (j == 0) {
                val = (t == 0) ? d : up + d;           // D[i,0] = D[i-1,0] + d
            } else if (t == 0) {
                val = cur + d;                          // D[0,j] = D[0,j-1] + d
            } else {
                const float diag = up_prev;
                val = fminf(fminf(diag + 2.0f * d, up + d), cur + d);
            }
            cur = val;
            up_prev = up;
            dbuf[k & 1][t] = cur;
        }
    }

    if (t == SEQ_N - 1) {
        dists[b] = cur / (2.0f * (float)SEQ_N);
    }
}

// Mean over the 64 per-batch distances -> single float output.
__global__ void dtw_reduce_kernel(const float* __restrict__ dists,
                                  float* __restrict__ out) {
    float v = dists[threadIdx.x] * (1.0f / (float)BATCH);
    #pragma unroll
    for (int o = 32; o > 0; o >>= 1) v += __shfl_down(v, o);
    if (threadIdx.x == 0) out[0] = v;
}

extern "C" void kernel_launch(void* const* d_in, const int* in_sizes, int n_in,
                              void* d_out, int out_size, void* d_ws, size_t ws_size,
                              hipStream_t stream) {
    const float* x = (const float*)d_in[0];
    const float* y = (const float*)d_in[1];
    float* out = (float*)d_out;
    float* dists = (float*)d_ws;  // 64 floats of scratch

    dtw_kernel<<<BATCH, SEQ_N, 0, stream>>>(x, y, dists);
    dtw_reduce_kernel<<<1, BATCH, 0, stream>>>(dists, out);
}

// Round 3
// 214.560 us; speedup vs baseline: 1.7724x; 1.7724x over previous
//
#include <hip/hip_runtime.h>

#define SEQ_N 1024   // sequence length (n == m == 1024)
#define BATCH 64     // batch size
#define RPL   16     // rows per lane (64 lanes * 16 = 1024)
#define NSTEP (SEQ_N + 63)

// One WAVE per batch element. Lane l owns rows [l*16, l*16+16) in registers.
// At step s, lane l computes column j = s - l for all its rows (lane-skewed
// wavefront). The only cross-lane dependency is lane l-1's bottom-row value
// from the previous step -> one __shfl_up per step, wave-synchronous, no
// barriers, no LDS in the dependency path.
//
// Cell recurrence (symmetric2, L1):
//   D = min(diag + 2d, up + d, left + d) = d + min3(diag + d, left, up)
// Only min3->add is on the serial up-chain (~8cy/cell); d and diag+d are
// off-chain and ILP-parallel (y_j is a single scalar per lane per step).
__global__ __launch_bounds__(64) void dtw_wave_kernel(const float* __restrict__ x,
                                                      const float* __restrict__ y,
                                                      float* __restrict__ dists) {
    __shared__ float sy[SEQ_N];
    const int b = blockIdx.x;
    const int l = threadIdx.x;   // 0..63

    // stage y in LDS (float4, coalesced)
    const float4* y4 = (const float4*)(y + b * SEQ_N);
    float4* sy4 = (float4*)sy;
    #pragma unroll
    for (int i = 0; i < SEQ_N / 4 / 64; ++i)
        sy4[l + i * 64] = y4[l + i * 64];

    // this lane's 16 x-rows -> registers
    float xr[RPL];
    const float4* x4 = (const float4*)(x + b * SEQ_N + l * RPL);
    #pragma unroll
    for (int i = 0; i < RPL / 4; ++i) {
        float4 v4 = x4[i];
        xr[i*4+0] = v4.x; xr[i*4+1] = v4.y; xr[i*4+2] = v4.z; xr[i*4+3] = v4.w;
    }
    __syncthreads();

    const float INF = 3.0e37f;
    float col[RPL];              // D[row_r, j_prev] for this lane's rows
    #pragma unroll
    for (int r = 0; r < RPL; ++r) col[r] = INF;
    float diag_top = INF;        // neighbor bottom from 2 steps ago = D[l*16-1, j-1]
    float bottom   = INF;        // this lane's col[15], exported via shuffle

    for (int s = 0; s < NSTEP; ++s) {
        const float up0 = __shfl_up(bottom, 1);   // all lanes execute (wave-uniform)
        const int j = s - l;
        if (j >= 0 && j < SEQ_N) {
            const float yj = sy[j];
            // top-row boundary: lane 0 has no row above; at j==0 the "up" slot
            // must yield D[0,0] = d, so feed 0 there and INF elsewhere.
            const float up = (l == 0) ? ((j == 0) ? 0.0f : INF) : up0;
            const float dg = (l == 0) ? INF : diag_top;

            float v = up;        // chain carrier: new col[r-1]
            float prev_old = 0.0f;
            #pragma unroll
            for (int r = 0; r < RPL; ++r) {
                const float d   = fabsf(xr[r] - yj);
                const float dgr = (r == 0) ? dg : prev_old;  // old col[r-1]
                const float t   = dgr + d;                   // off-chain
                prev_old = col[r];
                v = fminf(fminf(t, col[r]), v) + d;          // min3 + add (chain)
                col[r] = v;
            }
            diag_top = up;       // becomes diag for next column
            bottom   = v;
        }
    }

    if (l == 63) dists[b] = col[RPL - 1] * (1.0f / (2.0f * (float)SEQ_N));
}

// Mean over the 64 per-batch distances -> single float output.
__global__ void dtw_reduce_kernel(const float* __restrict__ dists,
                                  float* __restrict__ out) {
    float v = dists[threadIdx.x] * (1.0f / (float)BATCH);
    #pragma unroll
    for (int o = 32; o > 0; o >>= 1) v += __shfl_down(v, o);
    if (threadIdx.x == 0) out[0] = v;
}

extern "C" void kernel_launch(void* const* d_in, const int* in_sizes, int n_in,
                              void* d_out, int out_size, void* d_ws, size_t ws_size,
                              hipStream_t stream) {
    const float* x = (const float*)d_in[0];
    const float* y = (const float*)d_in[1];
    float* out = (float*)d_out;
    float* dists = (float*)d_ws;  // 64 floats of scratch

    dtw_wave_kernel<<<BATCH, 64, 0, stream>>>(x, y, dists);
    dtw_reduce_kernel<<<1, BATCH, 0, stream>>>(dists, out);
}

// Round 4
// 185.310 us; speedup vs baseline: 2.0521x; 1.1578x over previous
//
#include <hip/hip_runtime.h>

#define SEQ_N 1024   // sequence length (n == m == 1024)
#define BATCH 64     // batch size
#define RPL   16     // rows per lane (64 lanes * 16 = 1024)

// Wave-wide shift-up-by-1 via DPP (VALU pipe, no LDS/bpermute latency).
//   a = row_shr:1  -> lane i gets lane i-1 within each 16-lane row;
//                     lanes 0,16,32,48 invalid -> take `old` = INF
//   b = row_bcast15-> lanes 16-31 get lane 15, 32-47 get 31, 48-63 get 47
//   up = rowhead(16/32/48) ? b : a ; lane 0 ends up INF automatically.
__device__ __forceinline__ float shfl_up1_dpp(float v, bool rowhead, float inf) {
    int old = __float_as_int(inf);
    int src = __float_as_int(v);
    int a = __builtin_amdgcn_update_dpp(old, src, 0x111, 0xF, 0xF, false); // row_shr:1
    int b = __builtin_amdgcn_update_dpp(old, src, 0x142, 0xF, 0xF, false); // row_bcast15
    return __int_as_float(rowhead ? b : a);
}

// One WAVE per batch element; lane l owns rows [l*16, l*16+16) in registers.
// Lane-skewed wavefront: at step s, lane l computes column j = s - l.
// Cross-lane dep = lane l-1's bottom value from previous step, moved by DPP.
// Cell: D = min(diag+2d, up+d, left+d) = d + min3(diag+d, left, up)
//   -> v_sub, v_add(|.|), v_min3, v_add(|.|): 4 VALU per cell.
__global__ __launch_bounds__(64) void dtw_wave_kernel(const float* __restrict__ x,
                                                      const float* __restrict__ y,
                                                      float* __restrict__ dists) {
    __shared__ float sy[SEQ_N];
    const int b = blockIdx.x;
    const int l = threadIdx.x;   // 0..63
    const float INF = 3.0e37f;
    const bool rowhead = (l == 16) || (l == 32) || (l == 48);

    // stage y in LDS (float4, coalesced)
    const float4* y4 = (const float4*)(y + b * SEQ_N);
    float4* sy4 = (float4*)sy;
    #pragma unroll
    for (int i = 0; i < SEQ_N / 4 / 64; ++i)
        sy4[l + i * 64] = y4[l + i * 64];

    // this lane's 16 x-rows -> registers
    float xr[RPL];
    const float4* x4 = (const float4*)(x + b * SEQ_N + l * RPL);
    #pragma unroll
    for (int i = 0; i < RPL / 4; ++i) {
        float4 v4 = x4[i];
        xr[i*4+0] = v4.x; xr[i*4+1] = v4.y; xr[i*4+2] = v4.z; xr[i*4+3] = v4.w;
    }
    __syncthreads();

    float col[RPL];
    #pragma unroll
    for (int r = 0; r < RPL; ++r) col[r] = INF;
    float diag_top = INF;   // neighbor bottom from 2 steps ago
    float bottom   = INF;   // this lane's col[15]
    int   jv = -l;          // column index for the upcoming step
    float yj = sy[0];       // y[clamp(jv)] for the upcoming step (lane0: correct)

    // ---- the 16-cell chain, shared by all phases ----
    #define DTW_CELLS(UP, DG)                                              \
        {                                                                  \
            float v = (UP);                                                \
            float prev_old = 0.0f;                                         \
            _Pragma("unroll")                                              \
            for (int r = 0; r < RPL; ++r) {                                \
                const float diff = xr[r] - yj;                             \
                const float dgr  = (r == 0) ? (DG) : prev_old;             \
                const float t    = dgr + fabsf(diff);                      \
                prev_old = col[r];                                         \
                v = fminf(fminf(t, col[r]), v) + fabsf(diff);              \
                col[r] = v;                                                \
            }                                                              \
            diag_top = (UP);                                               \
            bottom   = v;                                                  \
        }

    #define DTW_PREFETCH()                                                 \
        const int jn = jv + 1;                                             \
        const int jc = min(max(jn, 0), SEQ_N - 1);                         \
        const float ynext = sy[jc];

    // ---- phase A: ramp-up, s in [0, 63): lanes l <= s active ----
    for (int s = 0; s < 63; ++s) {
        const float up_dpp = shfl_up1_dpp(bottom, rowhead, INF);
        DTW_PREFETCH();
        if (jv >= 0) {
            const float up = (l == 0) ? ((s == 0) ? 0.0f : INF) : up_dpp;
            const float dg = (l == 0) ? INF : diag_top;
            DTW_CELLS(up, dg);
        }
        yj = ynext; jv = jn;
    }

    // ---- phase B: steady, s in [63, 1024): ALL lanes active, no masks ----
    // lane 0: up_dpp == INF (old operand) and diag_top == INF by induction.
    for (int s = 63; s < SEQ_N; ++s) {
        const float up = shfl_up1_dpp(bottom, rowhead, INF);
        DTW_PREFETCH();
        DTW_CELLS(up, diag_top);
        yj = ynext; jv = jn;
    }

    // ---- phase C: ramp-down, s in [1024, 1087): lanes l >= s-1023 active ----
    for (int s = SEQ_N; s < SEQ_N + 63; ++s) {
        const float up = shfl_up1_dpp(bottom, rowhead, INF);
        DTW_PREFETCH();
        if (jv < SEQ_N) {
            DTW_CELLS(up, diag_top);
        }
        yj = ynext; jv = jn;
    }

    if (l == 63) dists[b] = col[RPL - 1] * (1.0f / (2.0f * (float)SEQ_N));
    #undef DTW_CELLS
    #undef DTW_PREFETCH
}

// Mean over the 64 per-batch distances -> single float output.
__global__ void dtw_reduce_kernel(const float* __restrict__ dists,
                                  float* __restrict__ out) {
    float v = dists[threadIdx.x] * (1.0f / (float)BATCH);
    #pragma unroll
    for (int o = 32; o > 0; o >>= 1) v += __shfl_down(v, o);
    if (threadIdx.x == 0) out[0] = v;
}

extern "C" void kernel_launch(void* const* d_in, const int* in_sizes, int n_in,
                              void* d_out, int out_size, void* d_ws, size_t ws_size,
                              hipStream_t stream) {
    const float* x = (const float*)d_in[0];
    const float* y = (const float*)d_in[1];
    float* out = (float*)d_out;
    float* dists = (float*)d_ws;  // 64 floats of scratch

    dtw_wave_kernel<<<BATCH, 64, 0, stream>>>(x, y, dists);
    dtw_reduce_kernel<<<1, BATCH, 0, stream>>>(dists, out);
}

// Round 5
// 156.591 us; speedup vs baseline: 2.4285x; 1.1834x over previous
//
#include <hip/hip_runtime.h>

#define SEQ_N 1024   // sequence length (n == m == 1024)
#define BATCH 64     // batch size
#define RPL   16     // rows per lane (64 lanes * 16 = 1024)
#define PAD_F 64     // LDS front pad (floats) -> unclamped yp[s] reads stay in-bounds
#define PAD_B 128    // LDS back pad

// Wave-wide shift-up-by-1 in ONE instruction: DPP wave_shr:1 (ctrl 0x138,
// GFX9/CDNA encoding). bound_ctrl=false -> lane 0 takes `fill` (INF), which is
// exactly the top-row boundary condition -> no lane-0 specials in steady state.
__device__ __forceinline__ float wave_shr1(float v, float fill) {
    return __int_as_float(__builtin_amdgcn_update_dpp(
        __float_as_int(fill), __float_as_int(v), 0x138, 0xF, 0xF, false));
}

// One WAVE per batch element; lane l owns rows [l*16, l*16+16) in registers.
// Lane-skewed wavefront: at step s, lane l computes column j = s - l.
//
// Cell: D = d + min3(diag + d, left, up). Split into:
//   off-chain: diff[r] = xr[r] - yj               (16 v_sub)
//              tt[r]   = old_col[r-1] + |diff[r]| (16 v_add, abs modifier)
//   chain:     v = min3(tt[r], col[r], v) + |diff[r]|  (v_min3 + v_add)
// -> exactly 4 VALU/cell, no v_movs (old col values are consumed into tt[]
//    BEFORE the chain overwrites col[]).
__global__ __launch_bounds__(64) void dtw_wave_kernel(const float* __restrict__ x,
                                                      const float* __restrict__ y,
                                                      float* __restrict__ dists) {
    __shared__ float sy_raw[PAD_F + SEQ_N + PAD_B];
    float* const sy = sy_raw + PAD_F;

    const int b = blockIdx.x;
    const int l = threadIdx.x;   // 0..63
    const float INF = 3.0e37f;

    // zero the pads (values are read by inactive lanes only, but keep them sane)
    sy_raw[l] = 0.0f;
    sy_raw[PAD_F + SEQ_N + l] = 0.0f;
    sy_raw[PAD_F + SEQ_N + 64 + l] = 0.0f;

    // stage y in LDS (float4, coalesced)
    const float4* y4 = (const float4*)(y + b * SEQ_N);
    float4* sy4 = (float4*)sy;
    #pragma unroll
    for (int i = 0; i < SEQ_N / 4 / 64; ++i)
        sy4[l + i * 64] = y4[l + i * 64];

    // this lane's 16 x-rows -> registers
    float xr[RPL];
    const float4* x4 = (const float4*)(x + b * SEQ_N + l * RPL);
    #pragma unroll
    for (int i = 0; i < RPL / 4; ++i) {
        float4 v4 = x4[i];
        xr[i*4+0] = v4.x; xr[i*4+1] = v4.y; xr[i*4+2] = v4.z; xr[i*4+3] = v4.w;
    }
    __syncthreads();

    float col[RPL];
    #pragma unroll
    for (int r = 0; r < RPL; ++r) col[r] = INF;
    float diag_top = INF;   // neighbor bottom from 2 steps ago
    float bottom   = INF;   // this lane's col[15]

    const float* const yp = sy - l;   // yp[s] == y[s - l] (pads make this safe)

#define DTW_STEP(YJ, UP, DG)                                               \
    {                                                                      \
        const float up_ = (UP);                                            \
        const float yj_ = (YJ);                                            \
        float diff[RPL], tt[RPL];                                          \
        _Pragma("unroll")                                                  \
        for (int r = 0; r < RPL; ++r) diff[r] = xr[r] - yj_;               \
        tt[0] = (DG) + fabsf(diff[0]);                                     \
        _Pragma("unroll")                                                  \
        for (int r = 1; r < RPL; ++r) tt[r] = col[r-1] + fabsf(diff[r]);   \
        float v = up_;                                                     \
        _Pragma("unroll")                                                  \
        for (int r = 0; r < RPL; ++r) {                                    \
            v = fminf(fminf(tt[r], col[r]), v) + fabsf(diff[r]);           \
            col[r] = v;                                                    \
        }                                                                  \
        diag_top = up_;                                                    \
        bottom   = v;                                                      \
    }

    // ---- phase A: s in [0, 64), lanes l <= s active ----
    float ycur = yp[0];   // garbage for l>0 (front pad) but unused until s==l
    for (int s = 0; s < 64; ++s) {
        const float up_dpp = wave_shr1(bottom, INF);
        const float ynext = yp[s + 1];
        if (s >= l) {
            const float up = (l == 0) ? ((s == 0) ? 0.0f : INF) : up_dpp;
            const float dg = (l == 0) ? INF : diag_top;
            DTW_STEP(ycur, up, dg);
        }
        ycur = ynext;
    }

    // ---- phase B: s in [64, 1024), ALL lanes active, zero masks ----
    // lane 0: up == INF from DPP fill; diag_top == INF by induction.
    // Unrolled by 2 with prefetch distance 2 (hides ~120cy ds_read latency).
    float y0 = ycur;       // y for step s
    float y1 = yp[65];     // y for step s+1
    for (int s = 64; s < SEQ_N; s += 2) {
        const float up0 = wave_shr1(bottom, INF);
        const float y2 = yp[s + 2];
        DTW_STEP(y0, up0, diag_top);
        const float up1 = wave_shr1(bottom, INF);
        const float y3 = yp[s + 3];
        DTW_STEP(y1, up1, diag_top);
        y0 = y2; y1 = y3;
    }

    // ---- phase C: s in [1024, 1087), lanes l >= s-1023 active ----
    for (int s = SEQ_N; s < SEQ_N + 63; ++s) {
        const float up = wave_shr1(bottom, INF);
        const float yn = yp[s + 2];
        if (s - l < SEQ_N) {
            DTW_STEP(y0, up, diag_top);
        }
        y0 = y1; y1 = yn;
    }
#undef DTW_STEP

    if (l == 63) dists[b] = col[RPL - 1] * (1.0f / (2.0f * (float)SEQ_N));
}

// Mean over the 64 per-batch distances -> single float output.
__global__ void dtw_reduce_kernel(const float* __restrict__ dists,
                                  float* __restrict__ out) {
    float v = dists[threadIdx.x] * (1.0f / (float)BATCH);
    #pragma unroll
    for (int o = 32; o > 0; o >>= 1) v += __shfl_down(v, o);
    if (threadIdx.x == 0) out[0] = v;
}

extern "C" void kernel_launch(void* const* d_in, const int* in_sizes, int n_in,
                              void* d_out, int out_size, void* d_ws, size_t ws_size,
                              hipStream_t stream) {
    const float* x = (const float*)d_in[0];
    const float* y = (const float*)d_in[1];
    float* out = (float*)d_out;
    float* dists = (float*)d_ws;  // 64 floats of scratch

    dtw_wave_kernel<<<BATCH, 64, 0, stream>>>(x, y, dists);
    dtw_reduce_kernel<<<1, BATCH, 0, stream>>>(dists, out);
}